// Round 1
// baseline (339.440 us; speedup 1.0000x reference)
//
#include <hip/hip_runtime.h>
#include <hip/hip_bf16.h>

#define B_ 4
#define N_ 4096
#define D_ 1024
#define H_ 16

typedef __attribute__((ext_vector_type(4))) float f32x4;
typedef __attribute__((ext_vector_type(8))) short s16x8;

__device__ __forceinline__ ushort f2bf(float f) {
  union { float f; unsigned u; } v; v.f = f;
  unsigned u = v.u;
  return (ushort)((u + 0x7fffu + ((u >> 16) & 1u)) >> 16);
}
__device__ __forceinline__ float bf2f(ushort h) {
  union { unsigned u; float f; } v; v.u = ((unsigned)h) << 16;
  return v.f;
}

__device__ __forceinline__ void gld16(const ushort* g, ushort* lds_base) {
  __builtin_amdgcn_global_load_lds(
      (const __attribute__((address_space(1))) unsigned int*)g,
      (__attribute__((address_space(3))) unsigned int*)lds_base, 16, 0, 0);
}

// ---------------- converts ----------------
__global__ void conv_w_kernel(const float* __restrict__ w0, const float* __restrict__ w1,
                              const float* __restrict__ w2, const float* __restrict__ w3,
                              ushort* __restrict__ dst) {
  const float* src = blockIdx.z == 0 ? w0 : blockIdx.z == 1 ? w1 : blockIdx.z == 2 ? w2 : w3;
  long i = ((long)blockIdx.x * 256 + threadIdx.x) * 8;
  ushort* d = dst + (long)blockIdx.z * (D_ * D_) + i;
  float4 a = *(const float4*)(src + i);
  float4 b = *(const float4*)(src + i + 4);
  s16x8 o;
  o[0] = (short)f2bf(a.x); o[1] = (short)f2bf(a.y); o[2] = (short)f2bf(a.z); o[3] = (short)f2bf(a.w);
  o[4] = (short)f2bf(b.x); o[5] = (short)f2bf(b.y); o[6] = (short)f2bf(b.z); o[7] = (short)f2bf(b.w);
  *(s16x8*)d = o;
}

__global__ void conv_x_kernel(const float* __restrict__ x0, const float* __restrict__ x1,
                              const float* __restrict__ x2, ushort* __restrict__ dst) {
  const float* src = blockIdx.z == 0 ? x0 : (blockIdx.z == 1 ? x1 : x2);
  long i = ((long)blockIdx.x * 256 + threadIdx.x) * 8;
  ushort* d = dst + (long)blockIdx.z * ((long)B_ * N_ * D_) + i;
  float4 a = *(const float4*)(src + i);
  float4 b = *(const float4*)(src + i + 4);
  s16x8 o;
  o[0] = (short)f2bf(a.x); o[1] = (short)f2bf(a.y); o[2] = (short)f2bf(a.z); o[3] = (short)f2bf(a.w);
  o[4] = (short)f2bf(b.x); o[5] = (short)f2bf(b.y); o[6] = (short)f2bf(b.z); o[7] = (short)f2bf(b.w);
  *(s16x8*)d = o;
}

// ---------------- gemm_bt: C[m,n] = sum_k A[m,k]*B[n,k] (+bias[n]) ----------------
// 128x128 tile, BK=32, 4 waves (2x2 of 64x64), m97 structure.
template <typename OT, bool BIAS>
__global__ __launch_bounds__(256, 2) void gemm_bt_kernel(
    const ushort* __restrict__ A, const ushort* __restrict__ Bm,
    OT* __restrict__ C, const float* __restrict__ bias,
    int M, int N, int K, long sA, long sB, long sC) {
  __shared__ ushort As[128 * 32];
  __shared__ ushort Bs[128 * 32];
  const int z = blockIdx.z;
  A += (long)z * sA; Bm += (long)z * sB; C += (long)z * sC;
  const int m0 = blockIdx.x * 128, n0 = blockIdx.y * 128;
  const int tid = threadIdx.x;
  const int wave = tid >> 6, lane = tid & 63;
  const int fl = lane & 15, fh = lane >> 4;
  const int wm = wave >> 1, wn = wave & 1;
  f32x4 acc[4][4] = {};
  const int c0 = tid;            // staging chunk 0 (16B each)
  const int c1 = tid + 256;      // staging chunk 1
  const int r0 = c0 >> 2, k80 = (c0 & 3) * 8;
  const int r1 = c1 >> 2, k81 = (c1 & 3) * 8;
  ushort* ldsA0 = As + wave * 512;
  ushort* ldsA1 = As + 2048 + wave * 512;
  ushort* ldsB0 = Bs + wave * 512;
  ushort* ldsB1 = Bs + 2048 + wave * 512;
  for (int kk = 0; kk < K; kk += 32) {
    __syncthreads();
    gld16(A + (long)(m0 + r0) * K + kk + k80, ldsA0);
    gld16(A + (long)(m0 + r1) * K + kk + k81, ldsA1);
    gld16(Bm + (long)(n0 + r0) * K + kk + k80, ldsB0);
    gld16(Bm + (long)(n0 + r1) * K + kk + k81, ldsB1);
    __syncthreads();
    s16x8 fa[4], fb[4];
#pragma unroll
    for (int i = 0; i < 4; ++i)
      fa[i] = *(const s16x8*)(As + (wm * 64 + i * 16 + fl) * 32 + fh * 8);
#pragma unroll
    for (int j = 0; j < 4; ++j)
      fb[j] = *(const s16x8*)(Bs + (wn * 64 + j * 16 + fl) * 32 + fh * 8);
#pragma unroll
    for (int i = 0; i < 4; ++i)
#pragma unroll
      for (int j = 0; j < 4; ++j)
        acc[i][j] = __builtin_amdgcn_mfma_f32_16x16x32_bf16(fa[i], fb[j], acc[i][j], 0, 0, 0);
  }
#pragma unroll
  for (int j = 0; j < 4; ++j) {
    int col = n0 + wn * 64 + j * 16 + fl;
    float bv = BIAS ? bias[col] : 0.0f;
#pragma unroll
    for (int i = 0; i < 4; ++i) {
#pragma unroll
      for (int r = 0; r < 4; ++r) {
        int row = m0 + wm * 64 + i * 16 + fh * 4 + r;
        float v = acc[i][j][r] + bv;
        if constexpr (sizeof(OT) == 2) C[(long)row * N + col] = (OT)f2bf(v);
        else C[(long)row * N + col] = v;
      }
    }
  }
}

// ---------------- q softmax (over 64 contiguous elems), *1/8, in place ----------------
__global__ void qsoftmax_kernel(ushort* __restrict__ Qp) {
  int gw = blockIdx.x * 4 + (threadIdx.x >> 6);
  int lane = threadIdx.x & 63;
  long off = (long)gw * 64 + lane;
  float x = bf2f(Qp[off]);
  float m = x;
#pragma unroll
  for (int o = 32; o; o >>= 1) m = fmaxf(m, __shfl_xor(m, o));
  float e = __expf(x - m);
  float s = e;
#pragma unroll
  for (int o = 32; o; o >>= 1) s += __shfl_xor(s, o);
  Qp[off] = f2bf(e * 0.125f / s);
}

// ---------------- k column softmax (over n), no max-subtract ----------------
__global__ void ksm1_kernel(const ushort* __restrict__ Kp, float* __restrict__ part) {
  int d = blockIdx.x * 256 + threadIdx.x;
  int chunk = blockIdx.y, b = blockIdx.z;
  const ushort* src = Kp + ((long)(b * N_ + chunk * 128)) * D_ + d;
  float s = 0.f;
  for (int r = 0; r < 128; ++r) s += __expf(bf2f(src[(long)r * D_]));
  part[((long)b * 32 + chunk) * D_ + d] = s;
}

__global__ void ksm2_kernel(const float* __restrict__ part, float* __restrict__ colinv) {
  int idx = blockIdx.x * 256 + threadIdx.x;  // b*1024+d
  int b = idx >> 10, d = idx & 1023;
  float s = 0.f;
  for (int c = 0; c < 32; ++c) s += part[((long)b * 32 + c) * D_ + d];
  colinv[idx] = 1.0f / s;
}

__global__ void ksm3_kernel(ushort* __restrict__ Kp, const float* __restrict__ colinv) {
  long i8 = ((long)blockIdx.x * 256 + threadIdx.x) * 8;
  int d = (int)(i8 & (D_ - 1));
  int b = (int)(i8 >> 22);
  s16x8 v = *(s16x8*)(Kp + i8);
  const float* inv = colinv + b * D_ + d;
  s16x8 o;
#pragma unroll
  for (int j = 0; j < 8; ++j)
    o[j] = (short)f2bf(__expf(bf2f((ushort)v[j])) * inv[j]);
  *(s16x8*)(Kp + i8) = o;
}

// ---------------- ctx partial: part[chunk][bh][dk][e] = sum_{n in chunk} k[n,dk]*v[n,e] ----------------
__global__ __launch_bounds__(256, 2) void ctx_partial_kernel(
    const ushort* __restrict__ Ksm, const ushort* __restrict__ Vp, float* __restrict__ part) {
  __shared__ ushort Ks[128 * 64];
  __shared__ ushort Vs[128 * 64];
  const int chunk = blockIdx.x;  // 32 chunks of 128 rows
  const int bh = blockIdx.y;     // 64
  const int b = bh >> 4, h = bh & 15;
  const long base = ((long)(b * N_ + chunk * 128)) * D_ + h * 64;
  const int tid = threadIdx.x, wave = tid >> 6, lane = tid & 63;
  const int fl = lane & 15, fh = lane >> 4;
#pragma unroll
  for (int i = 0; i < 4; ++i) {
    int c = i * 256 + tid;
    int r = c >> 3, k8 = (c & 7) * 8;
    ushort* lk = Ks + (long)(i * 256 + wave * 64) * 8;
    ushort* lv = Vs + (long)(i * 256 + wave * 64) * 8;
    gld16(Ksm + base + (long)r * D_ + k8, lk);
    gld16(Vp + base + (long)r * D_ + k8, lv);
  }
  __syncthreads();
  f32x4 acc[4] = {};
#pragma unroll
  for (int s = 0; s < 4; ++s) {  // n-slices of 32
    s16x8 fa;
#pragma unroll
    for (int j = 0; j < 8; ++j)
      fa[j] = (short)Ks[(s * 32 + fh * 8 + j) * 64 + wave * 16 + fl];
#pragma unroll
    for (int jt = 0; jt < 4; ++jt) {
      s16x8 fb;
#pragma unroll
      for (int j = 0; j < 8; ++j)
        fb[j] = (short)Vs[(s * 32 + fh * 8 + j) * 64 + jt * 16 + fl];
      acc[jt] = __builtin_amdgcn_mfma_f32_16x16x32_bf16(fa, fb, acc[jt], 0, 0, 0);
    }
  }
  float* dst = part + ((long)chunk * 64 + bh) * 4096;
#pragma unroll
  for (int jt = 0; jt < 4; ++jt)
#pragma unroll
    for (int r = 0; r < 4; ++r)
      dst[(wave * 16 + fh * 4 + r) * 64 + jt * 16 + fl] = acc[jt][r];
}

// ctxb[bh][dk][e] = bf16( sum_ch part + bv[h*64+e] )
__global__ void ctx_reduce_kernel(const float* __restrict__ part, const float* __restrict__ bv,
                                  ushort* __restrict__ ctxb) {
  int idx = blockIdx.x * 256 + threadIdx.x;  // bh*4096 + dk*64 + e
  int e = idx & 63;
  int h = (idx >> 12) & 15;
  float s = 0.f;
  for (int c = 0; c < 32; ++c) s += part[(long)c * 262144 + idx];
  s += bv[h * 64 + e];
  ctxb[idx] = f2bf(s);
}

// Mb[b][o, h*64+dk] = sum_e Wo[o, h*64+e] * ctx[b,h][dk,e]
__global__ __launch_bounds__(256, 2) void mb_kernel(
    const ushort* __restrict__ Wob, const ushort* __restrict__ ctxb, ushort* __restrict__ Mb) {
  const int o0 = blockIdx.x * 64, h = blockIdx.y, b = blockIdx.z;
  const int tid = threadIdx.x, wave = tid >> 6, lane = tid & 63;
  const int fl = lane & 15, fh = lane >> 4;
  const ushort* ctxh = ctxb + ((long)(b * 16 + h)) * 4096;
  f32x4 acc[4] = {};
#pragma unroll
  for (int s = 0; s < 2; ++s) {
    s16x8 fa = *(const s16x8*)(Wob + (long)(o0 + wave * 16 + fl) * D_ + h * 64 + s * 32 + fh * 8);
#pragma unroll
    for (int jt = 0; jt < 4; ++jt) {
      s16x8 fb = *(const s16x8*)(ctxh + (long)(jt * 16 + fl) * 64 + s * 32 + fh * 8);
      acc[jt] = __builtin_amdgcn_mfma_f32_16x16x32_bf16(fa, fb, acc[jt], 0, 0, 0);
    }
  }
  ushort* dst = Mb + (long)b * (D_ * D_);
#pragma unroll
  for (int jt = 0; jt < 4; ++jt)
#pragma unroll
    for (int r = 0; r < 4; ++r)
      dst[(long)(o0 + wave * 16 + fh * 4 + r) * D_ + h * 64 + jt * 16 + fl] = f2bf(acc[jt][r]);
}

// ---------------- launch ----------------
extern "C" void kernel_launch(void* const* d_in, const int* in_sizes, int n_in,
                              void* d_out, int out_size, void* d_ws, size_t ws_size,
                              hipStream_t stream) {
  const float* q_in = (const float*)d_in[0];
  const float* k_in = (const float*)d_in[1];
  const float* v_in = (const float*)d_in[2];
  const float* Wq = (const float*)d_in[3];
  const float* bq = (const float*)d_in[4];
  const float* Wv = (const float*)d_in[7];
  const float* bv = (const float*)d_in[8];
  const float* Wk = (const float*)d_in[5];
  const float* Wo = (const float*)d_in[9];
  const float* bo = (const float*)d_in[10];

  char* ws = (char*)d_ws;
  const long XSZ = (long)B_ * N_ * D_;  // 16777216 elems
  ushort* Xq = (ushort*)(ws + 0);
  ushort* Xk = (ushort*)(ws + 33554432);
  ushort* Xv = (ushort*)(ws + 67108864);
  ushort* Wb = (ushort*)(ws + 100663296);      // q,k,v,o each 1048576 elems
  ushort* Qp = (ushort*)(ws + 109051904);
  ushort* Kp = (ushort*)(ws + 142606336);
  ushort* Vp = (ushort*)(ws + 176160768);
  // aliased over X region (dead after projections):
  float* kpart = (float*)(ws + 0);             // [4][32][1024] f32
  float* colinv = (float*)(ws + 524288);       // [4][1024] f32
  float* ctxpart = (float*)(ws + 1048576);     // [32][64][4096] f32
  ushort* ctxb = (ushort*)(ws + 34603008);     // [64][64][64] bf16
  ushort* Mb = (ushort*)(ws + 35651584);       // [4][1024][1024] bf16

  ushort* Wbq = Wb;
  ushort* Wbk = Wb + 1048576;
  ushort* Wbv = Wb + 2097152;
  ushort* Wbo = Wb + 3145728;

  conv_w_kernel<<<dim3(512, 1, 4), 256, 0, stream>>>(Wq, Wk, Wv, Wo, Wb);
  conv_x_kernel<<<dim3(8192, 1, 3), 256, 0, stream>>>(q_in, k_in, v_in, Xq);

  // projections: M=16384, N=1024, K=1024
  gemm_bt_kernel<ushort, true><<<dim3(128, 8, 1), 256, 0, stream>>>(
      Xq, Wbq, Qp, bq, 16384, 1024, 1024, 0, 0, 0);
  gemm_bt_kernel<ushort, false><<<dim3(128, 8, 1), 256, 0, stream>>>(
      Xk, Wbk, Kp, nullptr, 16384, 1024, 1024, 0, 0, 0);
  gemm_bt_kernel<ushort, false><<<dim3(128, 8, 1), 256, 0, stream>>>(
      Xv, Wbv, Vp, nullptr, 16384, 1024, 1024, 0, 0, 0);

  qsoftmax_kernel<<<65536, 256, 0, stream>>>(Qp);
  ksm1_kernel<<<dim3(4, 32, 4), 256, 0, stream>>>(Kp, kpart);
  ksm2_kernel<<<16, 256, 0, stream>>>(kpart, colinv);
  ksm3_kernel<<<8192, 256, 0, stream>>>(Kp, colinv);

  ctx_partial_kernel<<<dim3(32, 64), 256, 0, stream>>>(Kp, Vp, ctxpart);
  ctx_reduce_kernel<<<1024, 256, 0, stream>>>(ctxpart, bv, ctxb);
  mb_kernel<<<dim3(16, 16, 4), 256, 0, stream>>>(Wbo, ctxb, Mb);

  // final: per-batch out = Qp_b @ Mb_b^T + bo  (fp32 out)
  gemm_bt_kernel<float, true><<<dim3(32, 8, 4), 256, 0, stream>>>(
      Qp, Mb, (float*)d_out, bo, 4096, 1024, 1024,
      (long)4096 * 1024, (long)1024 * 1024, (long)4096 * 1024);
}

// Round 2
// 292.654 us; speedup vs baseline: 1.1599x; 1.1599x over previous
//
#include <hip/hip_runtime.h>
#include <hip/hip_bf16.h>

#define B_ 4
#define N_ 4096
#define D_ 1024
#define H_ 16

typedef __attribute__((ext_vector_type(4))) float f32x4;
typedef __attribute__((ext_vector_type(8))) short s16x8;

__device__ __forceinline__ ushort f2bf(float f) {
  union { float f; unsigned u; } v; v.f = f;
  unsigned u = v.u;
  return (ushort)((u + 0x7fffu + ((u >> 16) & 1u)) >> 16);
}
__device__ __forceinline__ float bf2f(ushort h) {
  union { unsigned u; float f; } v; v.u = ((unsigned)h) << 16;
  return v.f;
}

__device__ __forceinline__ void gld16(const ushort* g, ushort* lds_base) {
  __builtin_amdgcn_global_load_lds(
      (const __attribute__((address_space(1))) unsigned int*)g,
      (__attribute__((address_space(3))) unsigned int*)lds_base, 16, 0, 0);
}

__device__ __forceinline__ s16x8 cvt8(float4 a, float4 b) {
  s16x8 o;
  o[0] = (short)f2bf(a.x); o[1] = (short)f2bf(a.y); o[2] = (short)f2bf(a.z); o[3] = (short)f2bf(a.w);
  o[4] = (short)f2bf(b.x); o[5] = (short)f2bf(b.y); o[6] = (short)f2bf(b.z); o[7] = (short)f2bf(b.w);
  return o;
}

// ---------------- converts (grid-stride, 8 independent chunks for ILP) ----------------
__global__ void conv_x_kernel(const float* __restrict__ x0, const float* __restrict__ x1,
                              const float* __restrict__ x2, ushort* __restrict__ dst) {
  const int z = blockIdx.z;
  const float* src = z == 0 ? x0 : (z == 1 ? x1 : x2);
  ushort* d = dst + (long)z * 16777216;
  const long i0 = ((long)blockIdx.x * 256 + threadIdx.x) * 8;
  const long STR = (long)1024 * 256 * 8;  // 2097152
  float4 va[8], vb[8];
#pragma unroll
  for (int u = 0; u < 8; ++u) {
    va[u] = *(const float4*)(src + i0 + u * STR);
    vb[u] = *(const float4*)(src + i0 + u * STR + 4);
  }
#pragma unroll
  for (int u = 0; u < 8; ++u) {
    *(s16x8*)(d + i0 + u * STR) = cvt8(va[u], vb[u]);
  }
}

__global__ void conv_w_kernel(const float* __restrict__ w0, const float* __restrict__ w1,
                              const float* __restrict__ w2, const float* __restrict__ w3,
                              ushort* __restrict__ dst) {
  const int z = blockIdx.z;
  const float* src = z == 0 ? w0 : z == 1 ? w1 : z == 2 ? w2 : w3;
  ushort* d = dst + (long)z * (D_ * D_);
  const long i0 = ((long)blockIdx.x * 256 + threadIdx.x) * 8;
  const long STR = (long)128 * 256 * 8;  // 262144
  float4 va[4], vb[4];
#pragma unroll
  for (int u = 0; u < 4; ++u) {
    va[u] = *(const float4*)(src + i0 + u * STR);
    vb[u] = *(const float4*)(src + i0 + u * STR + 4);
  }
#pragma unroll
  for (int u = 0; u < 4; ++u) {
    *(s16x8*)(d + i0 + u * STR) = cvt8(va[u], vb[u]);
  }
}

// ---------------- gemm_bt: C[m,n] = sum_k A[m,k]*B[n,k], fused epilogues ----------------
// EPI: 0 = plain bf16 store (V-proj), 1 = +bias, row-head softmax *1/8 (Q-proj),
//      2 = exp + column partial sums (K-proj), 3 = +bias, fp32 store (final)
template <int EPI>
__global__ __launch_bounds__(256, 2) void gemm_bt_kernel(
    const ushort* __restrict__ A, const ushort* __restrict__ Bm,
    void* __restrict__ Cv, const float* __restrict__ bias, float* __restrict__ kpart,
    int M, int N, int K, long sA, long sB, long sC) {
  __shared__ ushort As[128 * 32];
  __shared__ ushort Bs[128 * 32];
  const int z = blockIdx.z;
  A += (long)z * sA; Bm += (long)z * sB;
  const int m0 = blockIdx.x * 128, n0 = blockIdx.y * 128;
  const int tid = threadIdx.x;
  const int wave = tid >> 6, lane = tid & 63;
  const int fl = lane & 15, fh = lane >> 4;
  const int wm = wave >> 1, wn = wave & 1;
  f32x4 acc[4][4] = {};
  const int c0 = tid, c1 = tid + 256;
  const int r0 = c0 >> 2, k80 = (c0 & 3) * 8;
  const int r1 = c1 >> 2, k81 = (c1 & 3) * 8;
  ushort* ldsA0 = As + wave * 512;
  ushort* ldsA1 = As + 2048 + wave * 512;
  ushort* ldsB0 = Bs + wave * 512;
  ushort* ldsB1 = Bs + 2048 + wave * 512;
  for (int kk = 0; kk < K; kk += 32) {
    __syncthreads();
    gld16(A + (long)(m0 + r0) * K + kk + k80, ldsA0);
    gld16(A + (long)(m0 + r1) * K + kk + k81, ldsA1);
    gld16(Bm + (long)(n0 + r0) * K + kk + k80, ldsB0);
    gld16(Bm + (long)(n0 + r1) * K + kk + k81, ldsB1);
    __syncthreads();
    s16x8 fa[4], fb[4];
#pragma unroll
    for (int i = 0; i < 4; ++i)
      fa[i] = *(const s16x8*)(As + (wm * 64 + i * 16 + fl) * 32 + fh * 8);
#pragma unroll
    for (int j = 0; j < 4; ++j)
      fb[j] = *(const s16x8*)(Bs + (wn * 64 + j * 16 + fl) * 32 + fh * 8);
#pragma unroll
    for (int i = 0; i < 4; ++i)
#pragma unroll
      for (int j = 0; j < 4; ++j)
        acc[i][j] = __builtin_amdgcn_mfma_f32_16x16x32_bf16(fa[i], fb[j], acc[i][j], 0, 0, 0);
  }

  if constexpr (EPI == 0) {
    ushort* C = (ushort*)Cv;
#pragma unroll
    for (int j = 0; j < 4; ++j) {
      int col = n0 + wn * 64 + j * 16 + fl;
#pragma unroll
      for (int i = 0; i < 4; ++i)
#pragma unroll
        for (int r = 0; r < 4; ++r) {
          int row = m0 + wm * 64 + i * 16 + fh * 4 + r;
          C[(long)row * N + col] = f2bf(acc[i][j][r]);
        }
    }
  } else if constexpr (EPI == 1) {
    // Q: add bias, softmax over the 64-col head (cols n0+wn*64 .. +63), scale 1/8
    ushort* C = (ushort*)Cv;
    float bcol[4];
#pragma unroll
    for (int j = 0; j < 4; ++j) bcol[j] = bias[n0 + wn * 64 + j * 16 + fl];
#pragma unroll
    for (int i = 0; i < 4; ++i)
#pragma unroll
      for (int r = 0; r < 4; ++r) {
        float v[4];
#pragma unroll
        for (int j = 0; j < 4; ++j) v[j] = acc[i][j][r] + bcol[j];
        float m = fmaxf(fmaxf(v[0], v[1]), fmaxf(v[2], v[3]));
#pragma unroll
        for (int o = 1; o <= 8; o <<= 1) m = fmaxf(m, __shfl_xor(m, o));
        float e[4], s = 0.f;
#pragma unroll
        for (int j = 0; j < 4; ++j) { e[j] = __expf(v[j] - m); s += e[j]; }
#pragma unroll
        for (int o = 1; o <= 8; o <<= 1) s += __shfl_xor(s, o);
        float sc = 0.125f / s;
        int row = m0 + wm * 64 + i * 16 + fh * 4 + r;
#pragma unroll
        for (int j = 0; j < 4; ++j)
          C[(long)row * N + n0 + wn * 64 + j * 16 + fl] = f2bf(e[j] * sc);
      }
  } else if constexpr (EPI == 2) {
    // K: store exp(k), write per-block column partial sums (deterministic, no atomics)
    ushort* C = (ushort*)Cv;
    float csum[4] = {};
#pragma unroll
    for (int j = 0; j < 4; ++j) {
      int col = n0 + wn * 64 + j * 16 + fl;
#pragma unroll
      for (int i = 0; i < 4; ++i)
#pragma unroll
        for (int r = 0; r < 4; ++r) {
          int row = m0 + wm * 64 + i * 16 + fh * 4 + r;
          float e = __expf(acc[i][j][r]);
          csum[j] += e;
          C[(long)row * N + col] = f2bf(e);
        }
    }
#pragma unroll
    for (int j = 0; j < 4; ++j) {
#pragma unroll
      for (int o = 16; o <= 32; o <<= 1) csum[j] += __shfl_xor(csum[j], o);
    }
    if (fh == 0) {
      int b = m0 >> 12;
      int chunk = ((m0 & 4095) >> 7) * 2 + wm;
#pragma unroll
      for (int j = 0; j < 4; ++j)
        kpart[(long)b * 65536 + (long)chunk * 1024 + n0 + wn * 64 + j * 16 + fl] = csum[j];
    }
  } else {
    // final: fp32 store + bias
    float* C = (float*)Cv + (long)z * sC;
#pragma unroll
    for (int j = 0; j < 4; ++j) {
      int col = n0 + wn * 64 + j * 16 + fl;
      float bv = bias[col];
#pragma unroll
      for (int i = 0; i < 4; ++i)
#pragma unroll
        for (int r = 0; r < 4; ++r) {
          int row = m0 + wm * 64 + i * 16 + fh * 4 + r;
          C[(long)row * N + col] = acc[i][j][r] + bv;
        }
    }
  }
}

// ---------------- colinv[b][d] = 1 / sum_c kpart[b][c][d] ----------------
__global__ void ksm2_kernel(const float* __restrict__ kpart, float* __restrict__ colinv) {
  int idx = blockIdx.x * 256 + threadIdx.x;  // b*1024+d
  int b = idx >> 10, d = idx & 1023;
  float s = 0.f;
  for (int c = 0; c < 64; ++c) s += kpart[(long)b * 65536 + (long)c * 1024 + d];
  colinv[idx] = 1.0f / s;
}

// ---------------- ctx partial: part[chunk][bh][dk][e] = sum_{n in chunk(512)} expk[n,dk]*v[n,e] ----------------
__global__ __launch_bounds__(256, 2) void ctx_partial_kernel(
    const ushort* __restrict__ Ksm, const ushort* __restrict__ Vp, float* __restrict__ part) {
  __shared__ ushort Ks[128 * 64];
  __shared__ ushort Vs[128 * 64];
  const int chunk = blockIdx.x;  // 8 chunks of 512 rows
  const int bh = blockIdx.y;     // 64
  const int b = bh >> 4, h = bh & 15;
  const int tid = threadIdx.x, wave = tid >> 6, lane = tid & 63;
  const int fl = lane & 15, fh = lane >> 4;
  f32x4 acc[4] = {};
  for (int t = 0; t < 4; ++t) {
    const long base = ((long)(b * N_ + chunk * 512 + t * 128)) * D_ + h * 64;
    __syncthreads();
#pragma unroll
    for (int i = 0; i < 4; ++i) {
      int c = i * 256 + tid;
      int r = c >> 3, k8 = (c & 7) * 8;
      ushort* lk = Ks + (long)(i * 256 + wave * 64) * 8;
      ushort* lv = Vs + (long)(i * 256 + wave * 64) * 8;
      gld16(Ksm + base + (long)r * D_ + k8, lk);
      gld16(Vp + base + (long)r * D_ + k8, lv);
    }
    __syncthreads();
#pragma unroll
    for (int s = 0; s < 4; ++s) {  // n-slices of 32
      s16x8 fa;
#pragma unroll
      for (int j = 0; j < 8; ++j)
        fa[j] = (short)Ks[(s * 32 + fh * 8 + j) * 64 + wave * 16 + fl];
#pragma unroll
      for (int jt = 0; jt < 4; ++jt) {
        s16x8 fb;
#pragma unroll
        for (int j = 0; j < 8; ++j)
          fb[j] = (short)Vs[(s * 32 + fh * 8 + j) * 64 + jt * 16 + fl];
        acc[jt] = __builtin_amdgcn_mfma_f32_16x16x32_bf16(fa, fb, acc[jt], 0, 0, 0);
      }
    }
  }
  float* dst = part + ((long)chunk * 64 + bh) * 4096;
#pragma unroll
  for (int jt = 0; jt < 4; ++jt)
#pragma unroll
    for (int r = 0; r < 4; ++r)
      dst[(wave * 16 + fh * 4 + r) * 64 + jt * 16 + fl] = acc[jt][r];
}

// ctxb[bh][dk][e] = bf16( colinv[b,h*64+dk] * sum_ch part + bv[h*64+e] )
__global__ void ctx_reduce_kernel(const float* __restrict__ part, const float* __restrict__ bv,
                                  const float* __restrict__ colinv, ushort* __restrict__ ctxb) {
  int idx = blockIdx.x * 256 + threadIdx.x;  // bh*4096 + dk*64 + e
  int e = idx & 63;
  int dk = (idx >> 6) & 63;
  int h = (idx >> 12) & 15;
  int b = idx >> 16;
  float s = 0.f;
#pragma unroll
  for (int c = 0; c < 8; ++c) s += part[(long)c * 262144 + idx];
  ctxb[idx] = f2bf(s * colinv[b * 1024 + h * 64 + dk] + bv[h * 64 + e]);
}

// Mb[b][o, h*64+dk] = sum_e Wo[o, h*64+e] * ctx[b,h][dk,e]
__global__ __launch_bounds__(256, 2) void mb_kernel(
    const ushort* __restrict__ Wob, const ushort* __restrict__ ctxb, ushort* __restrict__ Mb) {
  const int o0 = blockIdx.x * 64, h = blockIdx.y, b = blockIdx.z;
  const int tid = threadIdx.x, wave = tid >> 6, lane = tid & 63;
  const int fl = lane & 15, fh = lane >> 4;
  const ushort* ctxh = ctxb + ((long)(b * 16 + h)) * 4096;
  f32x4 acc[4] = {};
#pragma unroll
  for (int s = 0; s < 2; ++s) {
    s16x8 fa = *(const s16x8*)(Wob + (long)(o0 + wave * 16 + fl) * D_ + h * 64 + s * 32 + fh * 8);
#pragma unroll
    for (int jt = 0; jt < 4; ++jt) {
      s16x8 fb = *(const s16x8*)(ctxh + (long)(jt * 16 + fl) * 64 + s * 32 + fh * 8);
      acc[jt] = __builtin_amdgcn_mfma_f32_16x16x32_bf16(fa, fb, acc[jt], 0, 0, 0);
    }
  }
  ushort* dst = Mb + (long)b * (D_ * D_);
#pragma unroll
  for (int jt = 0; jt < 4; ++jt)
#pragma unroll
    for (int r = 0; r < 4; ++r)
      dst[(long)(o0 + wave * 16 + fh * 4 + r) * D_ + h * 64 + jt * 16 + fl] = f2bf(acc[jt][r]);
}

// ---------------- launch ----------------
extern "C" void kernel_launch(void* const* d_in, const int* in_sizes, int n_in,
                              void* d_out, int out_size, void* d_ws, size_t ws_size,
                              hipStream_t stream) {
  const float* q_in = (const float*)d_in[0];
  const float* k_in = (const float*)d_in[1];
  const float* v_in = (const float*)d_in[2];
  const float* Wq = (const float*)d_in[3];
  const float* bq = (const float*)d_in[4];
  const float* Wk = (const float*)d_in[5];
  const float* Wv = (const float*)d_in[7];
  const float* bv = (const float*)d_in[8];
  const float* Wo = (const float*)d_in[9];
  const float* bo = (const float*)d_in[10];

  char* ws = (char*)d_ws;
  ushort* Xq = (ushort*)(ws + 0);
  ushort* Xk = (ushort*)(ws + 33554432);
  ushort* Xv = (ushort*)(ws + 67108864);
  ushort* Wb = (ushort*)(ws + 100663296);
  ushort* Qp = (ushort*)(ws + 109051904);
  ushort* Kp = (ushort*)(ws + 142606336);
  ushort* Vp = (ushort*)(ws + 176160768);
  // aliased over Xq region (dead after Q-projection):
  float* kpart = (float*)(ws + 0);             // [4][64][1024] f32 = 1 MB
  float* colinv = (float*)(ws + 1048576);      // [4][1024] f32
  float* ctxpart = (float*)(ws + 2097152);     // [8][64][4096] f32 = 8 MB
  ushort* ctxb = (ushort*)(ws + 10485760);     // [64][64][64] bf16
  ushort* Mb = (ushort*)(ws + 11534336);       // [4][1024][1024] bf16

  ushort* Wbq = Wb;
  ushort* Wbk = Wb + 1048576;
  ushort* Wbv = Wb + 2097152;
  ushort* Wbo = Wb + 3145728;

  conv_w_kernel<<<dim3(128, 1, 4), 256, 0, stream>>>(Wq, Wk, Wv, Wo, Wb);
  conv_x_kernel<<<dim3(1024, 1, 3), 256, 0, stream>>>(q_in, k_in, v_in, Xq);

  // projections: M=16384, N=1024, K=1024
  gemm_bt_kernel<1><<<dim3(128, 8, 1), 256, 0, stream>>>(
      Xq, Wbq, Qp, bq, nullptr, 16384, 1024, 1024, 0, 0, 0);
  gemm_bt_kernel<2><<<dim3(128, 8, 1), 256, 0, stream>>>(
      Xk, Wbk, Kp, nullptr, kpart, 16384, 1024, 1024, 0, 0, 0);
  gemm_bt_kernel<0><<<dim3(128, 8, 1), 256, 0, stream>>>(
      Xv, Wbv, Vp, nullptr, nullptr, 16384, 1024, 1024, 0, 0, 0);

  ksm2_kernel<<<16, 256, 0, stream>>>(kpart, colinv);

  ctx_partial_kernel<<<dim3(8, 64), 256, 0, stream>>>(Kp, Vp, ctxpart);
  ctx_reduce_kernel<<<1024, 256, 0, stream>>>(ctxpart, bv, colinv, ctxb);
  mb_kernel<<<dim3(16, 16, 4), 256, 0, stream>>>(Wbo, ctxb, Mb);

  // final: per-batch out = Qp_b @ Mb_b^T + bo  (fp32 out)
  gemm_bt_kernel<3><<<dim3(32, 8, 4), 256, 0, stream>>>(
      Qp, Mb, (float*)d_out, bo, nullptr, 4096, 1024, 1024,
      (long)4096 * 1024, (long)1024 * 1024, (long)4096 * 1024);
}

// Round 4
// 263.515 us; speedup vs baseline: 1.2881x; 1.1106x over previous
//
#include <hip/hip_runtime.h>
#include <hip/hip_bf16.h>

#define B_ 4
#define N_ 4096
#define D_ 1024
#define H_ 16

typedef __attribute__((ext_vector_type(4))) float f32x4;
typedef __attribute__((ext_vector_type(8))) short s16x8;

__device__ __forceinline__ ushort f2bf(float f) {
  union { float f; unsigned u; } v; v.f = f;
  unsigned u = v.u;
  return (ushort)((u + 0x7fffu + ((u >> 16) & 1u)) >> 16);
}

__device__ __forceinline__ void gld16(const ushort* g, ushort* lds_base) {
  __builtin_amdgcn_global_load_lds(
      (const __attribute__((address_space(1))) unsigned int*)g,
      (__attribute__((address_space(3))) unsigned int*)lds_base, 16, 0, 0);
}

__device__ __forceinline__ unsigned cvtpk(float lo, float hi) {
  unsigned r;
  asm("v_cvt_pk_bf16_f32 %0, %1, %2" : "=v"(r) : "v"(lo), "v"(hi));
  return r;
}

// ---------------- weight convert ----------------
__global__ void conv_w_kernel(const float* __restrict__ w0, const float* __restrict__ w1,
                              const float* __restrict__ w2, const float* __restrict__ w3,
                              ushort* __restrict__ dst) {
  const int z = blockIdx.z;
  const float* src = z == 0 ? w0 : z == 1 ? w1 : z == 2 ? w2 : w3;
  ushort* d = dst + (long)z * (D_ * D_);
  const long i0 = ((long)blockIdx.x * 256 + threadIdx.x) * 8;
  const long STR = (long)128 * 256 * 8;
#pragma unroll
  for (int u = 0; u < 4; ++u) {
    f32x4 a = *(const f32x4*)(src + i0 + u * STR);
    f32x4 b = *(const f32x4*)(src + i0 + u * STR + 4);
    s16x8 o;
    o[0] = (short)f2bf(a[0]); o[1] = (short)f2bf(a[1]); o[2] = (short)f2bf(a[2]); o[3] = (short)f2bf(a[3]);
    o[4] = (short)f2bf(b[0]); o[5] = (short)f2bf(b[1]); o[6] = (short)f2bf(b[2]); o[7] = (short)f2bf(b[3]);
    *(s16x8*)(d + i0 + u * STR) = o;
  }
}

// ---------------- gemm_bt: C[m,n] = sum_k A[m,k]*B[n,k], fused epilogues ----------------
// AFP32: A operand is fp32, converted during reg-staging.
// EPI: 0 = plain bf16 store (V-proj), 1 = +bias, row-head softmax *1/8 (Q-proj),
//      2 = exp + column partial sums (K-proj), 3 = +bias, fp32 store (final)
// Grid: 1-D of MT*8 blocks (z = batch). XCD-aware remap: each XCD owns a
// contiguous m-range, iterates n fastest -> A panel L2-hit, B L2-resident.
template <int EPI, bool AFP32>
__global__ __launch_bounds__(256, 2) void gemm_bt_kernel(
    const void* __restrict__ Av, const ushort* __restrict__ Bm,
    void* __restrict__ Cv, const float* __restrict__ bias, float* __restrict__ kpart,
    int MT, int K, long sA, long sB, long sC) {
  __shared__ ushort As[128 * 32];
  __shared__ ushort Bs[128 * 32];
  const int z = blockIdx.z;
  Bm += (long)z * sB;
  const int lin = blockIdx.x;
  const int xcd = lin & 7, idx = lin >> 3;
  const int mpx = MT >> 3;  // m-tiles per XCD
  const int m0 = (xcd * mpx + (idx >> 3)) * 128;
  const int n0 = (idx & 7) * 128;
  const int N = 1024;
  const int tid = threadIdx.x;
  const int wave = tid >> 6, lane = tid & 63;
  const int fl = lane & 15, fh = lane >> 4;
  const int wm = wave >> 1, wn = wave & 1;
  f32x4 acc[4][4] = {};
  // B staging (global_load_lds, 16B chunks)
  const int rb0 = tid >> 2, kb0 = (tid & 3) * 8;
  const int rb1 = (tid + 256) >> 2, kb1 = ((tid + 256) & 3) * 8;
  ushort* ldsB0 = Bs + wave * 512;
  ushort* ldsB1 = Bs + 2048 + wave * 512;
  // A staging (bf16 path mirrors B; fp32 path reg-staged)
  ushort* ldsA0 = As + wave * 512;
  ushort* ldsA1 = As + 2048 + wave * 512;

  const float* Af = (const float*)Av;
  const ushort* Ab = (const ushort*)Av + (long)z * sA;
  // fp32-A addressing: thread covers rows (tid>>3)+u*32, floats (tid&7)*4..+3
  const float* ap = AFP32 ? (Af + (long)(m0 + (tid >> 3)) * K + (tid & 7) * 4) : nullptr;
  ushort* wp = As + (tid >> 3) * 32 + (tid & 7) * 4;
  f32x4 areg[4];
  if constexpr (AFP32) {
#pragma unroll
    for (int u = 0; u < 4; ++u) areg[u] = *(const f32x4*)(ap + u * 32 * 1024);
  }

  for (int kk = 0; kk < K; kk += 32) {
    __syncthreads();
    gld16(Bm + (long)(n0 + rb0) * K + kk + kb0, ldsB0);
    gld16(Bm + (long)(n0 + rb1) * K + kk + kb1, ldsB1);
    if constexpr (AFP32) {
#pragma unroll
      for (int u = 0; u < 4; ++u) {
        uint2 w;
        w.x = cvtpk(areg[u][0], areg[u][1]);
        w.y = cvtpk(areg[u][2], areg[u][3]);
        *(uint2*)(wp + u * 1024) = w;
      }
      if (kk + 32 < K) {
#pragma unroll
        for (int u = 0; u < 4; ++u)
          areg[u] = *(const f32x4*)(ap + u * 32 * 1024 + kk + 32);
      }
    } else {
      gld16(Ab + (long)(m0 + rb0) * K + kk + kb0, ldsA0);
      gld16(Ab + (long)(m0 + rb1) * K + kk + kb1, ldsA1);
    }
    __syncthreads();
    s16x8 fa[4], fb[4];
#pragma unroll
    for (int i = 0; i < 4; ++i)
      fa[i] = *(const s16x8*)(As + (wm * 64 + i * 16 + fl) * 32 + fh * 8);
#pragma unroll
    for (int j = 0; j < 4; ++j)
      fb[j] = *(const s16x8*)(Bs + (wn * 64 + j * 16 + fl) * 32 + fh * 8);
#pragma unroll
    for (int i = 0; i < 4; ++i)
#pragma unroll
      for (int j = 0; j < 4; ++j)
        acc[i][j] = __builtin_amdgcn_mfma_f32_16x16x32_bf16(fa[i], fb[j], acc[i][j], 0, 0, 0);
  }

  if constexpr (EPI == 0) {
    ushort* C = (ushort*)Cv;
#pragma unroll
    for (int j = 0; j < 4; ++j) {
      int col = n0 + wn * 64 + j * 16 + fl;
#pragma unroll
      for (int i = 0; i < 4; ++i)
#pragma unroll
        for (int r = 0; r < 4; ++r) {
          int row = m0 + wm * 64 + i * 16 + fh * 4 + r;
          C[(long)row * N + col] = f2bf(acc[i][j][r]);
        }
    }
  } else if constexpr (EPI == 1) {
    // Q: add bias, softmax over the 64-col head, scale 1/8
    ushort* C = (ushort*)Cv;
    float bcol[4];
#pragma unroll
    for (int j = 0; j < 4; ++j) bcol[j] = bias[n0 + wn * 64 + j * 16 + fl];
#pragma unroll
    for (int i = 0; i < 4; ++i)
#pragma unroll
      for (int r = 0; r < 4; ++r) {
        float v[4];
#pragma unroll
        for (int j = 0; j < 4; ++j) v[j] = acc[i][j][r] + bcol[j];
        float m = fmaxf(fmaxf(v[0], v[1]), fmaxf(v[2], v[3]));
#pragma unroll
        for (int o = 1; o <= 8; o <<= 1) m = fmaxf(m, __shfl_xor(m, o));
        float e[4], s = 0.f;
#pragma unroll
        for (int j = 0; j < 4; ++j) { e[j] = __expf(v[j] - m); s += e[j]; }
#pragma unroll
        for (int o = 1; o <= 8; o <<= 1) s += __shfl_xor(s, o);
        float sc = 0.125f / s;
        int row = m0 + wm * 64 + i * 16 + fh * 4 + r;
#pragma unroll
        for (int j = 0; j < 4; ++j)
          C[(long)row * N + n0 + wn * 64 + j * 16 + fl] = f2bf(e[j] * sc);
      }
  } else if constexpr (EPI == 2) {
    // K: store exp(k), per-block column partial sums (deterministic)
    ushort* C = (ushort*)Cv;
    float csum[4] = {};
#pragma unroll
    for (int j = 0; j < 4; ++j) {
      int col = n0 + wn * 64 + j * 16 + fl;
#pragma unroll
      for (int i = 0; i < 4; ++i)
#pragma unroll
        for (int r = 0; r < 4; ++r) {
          int row = m0 + wm * 64 + i * 16 + fh * 4 + r;
          float e = __expf(acc[i][j][r]);
          csum[j] += e;
          C[(long)row * N + col] = f2bf(e);
        }
    }
#pragma unroll
    for (int j = 0; j < 4; ++j) {
#pragma unroll
      for (int o = 16; o <= 32; o <<= 1) csum[j] += __shfl_xor(csum[j], o);
    }
    if (fh == 0) {
      int b = m0 >> 12;
      int chunk = ((m0 & 4095) >> 7) * 2 + wm;
#pragma unroll
      for (int j = 0; j < 4; ++j)
        kpart[(long)b * 65536 + (long)chunk * 1024 + n0 + wn * 64 + j * 16 + fl] = csum[j];
    }
  } else {
    // final: fp32 store + bias
    float* C = (float*)Cv + (long)z * sC;
#pragma unroll
    for (int j = 0; j < 4; ++j) {
      int col = n0 + wn * 64 + j * 16 + fl;
      float bv = bias[col];
#pragma unroll
      for (int i = 0; i < 4; ++i)
#pragma unroll
        for (int r = 0; r < 4; ++r) {
          int row = m0 + wm * 64 + i * 16 + fh * 4 + r;
          C[(long)row * N + col] = acc[i][j][r] + bv;
        }
    }
  }
}

// ---------------- colinv[b][d] = 1 / sum_c kpart[b][c][d] ----------------
__global__ void ksm2_kernel(const float* __restrict__ kpart, float* __restrict__ colinv) {
  int idx = blockIdx.x * 256 + threadIdx.x;  // b*1024+d
  int b = idx >> 10, d = idx & 1023;
  float s = 0.f;
  for (int c = 0; c < 64; ++c) s += kpart[(long)b * 65536 + (long)c * 1024 + d];
  colinv[idx] = 1.0f / s;
}

// ---------------- ctx partial: part[chunk][bh][dk][e] = sum_{n in chunk(512)} expk[n,dk]*v[n,e] ----------------
__global__ __launch_bounds__(256, 2) void ctx_partial_kernel(
    const ushort* __restrict__ Ksm, const ushort* __restrict__ Vp, float* __restrict__ part) {
  __shared__ ushort Ks[128 * 64];
  __shared__ ushort Vs[128 * 64];
  const int chunk = blockIdx.x;  // 8 chunks of 512 rows
  const int bh = blockIdx.y;     // 64
  const int b = bh >> 4, h = bh & 15;
  const int tid = threadIdx.x, wave = tid >> 6, lane = tid & 63;
  const int fl = lane & 15, fh = lane >> 4;
  f32x4 acc[4] = {};
  for (int t = 0; t < 4; ++t) {
    const long base = ((long)(b * N_ + chunk * 512 + t * 128)) * D_ + h * 64;
    __syncthreads();
#pragma unroll
    for (int i = 0; i < 4; ++i) {
      int c = i * 256 + tid;
      int r = c >> 3, k8 = (c & 7) * 8;
      ushort* lk = Ks + (long)(i * 256 + wave * 64) * 8;
      ushort* lv = Vs + (long)(i * 256 + wave * 64) * 8;
      gld16(Ksm + base + (long)r * D_ + k8, lk);
      gld16(Vp + base + (long)r * D_ + k8, lv);
    }
    __syncthreads();
#pragma unroll
    for (int s = 0; s < 4; ++s) {  // n-slices of 32
      s16x8 fa;
#pragma unroll
      for (int j = 0; j < 8; ++j)
        fa[j] = (short)Ks[(s * 32 + fh * 8 + j) * 64 + wave * 16 + fl];
#pragma unroll
      for (int jt = 0; jt < 4; ++jt) {
        s16x8 fb;
#pragma unroll
        for (int j = 0; j < 8; ++j)
          fb[j] = (short)Vs[(s * 32 + fh * 8 + j) * 64 + jt * 16 + fl];
        acc[jt] = __builtin_amdgcn_mfma_f32_16x16x32_bf16(fa, fb, acc[jt], 0, 0, 0);
      }
    }
  }
  float* dst = part + ((long)chunk * 64 + bh) * 4096;
#pragma unroll
  for (int jt = 0; jt < 4; ++jt)
#pragma unroll
    for (int r = 0; r < 4; ++r)
      dst[(wave * 16 + fh * 4 + r) * 64 + jt * 16 + fl] = acc[jt][r];
}

// ctxb[bh][dk][e] = bf16( colinv[b,h*64+dk] * sum_ch part + bv[h*64+e] )
__global__ void ctx_reduce_kernel(const float* __restrict__ part, const float* __restrict__ bv,
                                  const float* __restrict__ colinv, ushort* __restrict__ ctxb) {
  int idx = blockIdx.x * 256 + threadIdx.x;
  int e = idx & 63;
  int dk = (idx >> 6) & 63;
  int h = (idx >> 12) & 15;
  int b = idx >> 16;
  float s = 0.f;
#pragma unroll
  for (int c = 0; c < 8; ++c) s += part[(long)c * 262144 + idx];
  ctxb[idx] = f2bf(s * colinv[b * 1024 + h * 64 + dk] + bv[h * 64 + e]);
}

// Mb[b][o, h*64+dk] = sum_e Wo[o, h*64+e] * ctx[b,h][dk,e]
__global__ __launch_bounds__(256, 2) void mb_kernel(
    const ushort* __restrict__ Wob, const ushort* __restrict__ ctxb, ushort* __restrict__ Mb) {
  const int o0 = blockIdx.x * 64, h = blockIdx.y, b = blockIdx.z;
  const int tid = threadIdx.x, wave = tid >> 6, lane = tid & 63;
  const int fl = lane & 15, fh = lane >> 4;
  const ushort* ctxh = ctxb + ((long)(b * 16 + h)) * 4096;
  f32x4 acc[4] = {};
#pragma unroll
  for (int s = 0; s < 2; ++s) {
    s16x8 fa = *(const s16x8*)(Wob + (long)(o0 + wave * 16 + fl) * D_ + h * 64 + s * 32 + fh * 8);
#pragma unroll
    for (int jt = 0; jt < 4; ++jt) {
      s16x8 fb = *(const s16x8*)(ctxh + (long)(jt * 16 + fl) * 64 + s * 32 + fh * 8);
      acc[jt] = __builtin_amdgcn_mfma_f32_16x16x32_bf16(fa, fb, acc[jt], 0, 0, 0);
    }
  }
  ushort* dst = Mb + (long)b * (D_ * D_);
#pragma unroll
  for (int jt = 0; jt < 4; ++jt)
#pragma unroll
    for (int r = 0; r < 4; ++r)
      dst[(long)(o0 + wave * 16 + fh * 4 + r) * D_ + h * 64 + jt * 16 + fl] = f2bf(acc[jt][r]);
}

// ---------------- launch ----------------
extern "C" void kernel_launch(void* const* d_in, const int* in_sizes, int n_in,
                              void* d_out, int out_size, void* d_ws, size_t ws_size,
                              hipStream_t stream) {
  const float* q_in = (const float*)d_in[0];
  const float* k_in = (const float*)d_in[1];
  const float* v_in = (const float*)d_in[2];
  const float* Wq = (const float*)d_in[3];
  const float* bq = (const float*)d_in[4];
  const float* Wk = (const float*)d_in[5];
  const float* Wv = (const float*)d_in[7];
  const float* bv = (const float*)d_in[8];
  const float* Wo = (const float*)d_in[9];
  const float* bo = (const float*)d_in[10];

  char* ws = (char*)d_ws;
  ushort* Wb = (ushort*)(ws + 0);              // 4 x 1024^2 bf16 = 8 MB
  ushort* Qp = (ushort*)(ws + 8388608);        // 32 MB
  ushort* Kp = (ushort*)(ws + 41943040);       // 32 MB
  ushort* Vp = (ushort*)(ws + 75497472);       // 32 MB
  float* kpart = (float*)(ws + 109051904);     // [4][64][1024] f32 = 1 MB
  float* colinv = (float*)(ws + 110100480);    // 16 KB
  float* ctxpart = (float*)(ws + 110116864);   // [8][64][4096] f32 = 8 MB
  ushort* ctxb = (ushort*)(ws + 118505472);    // 512 KB
  ushort* Mb = (ushort*)(ws + 119029760);      // 8 MB

  ushort* Wbq = Wb;
  ushort* Wbk = Wb + 1048576;
  ushort* Wbv = Wb + 2097152;
  ushort* Wbo = Wb + 3145728;

  conv_w_kernel<<<dim3(128, 1, 4), 256, 0, stream>>>(Wq, Wk, Wv, Wo, Wb);

  // projections: fp32 A read directly, M=16384 (MT=128), N=1024, K=1024
  gemm_bt_kernel<1, true><<<dim3(1024, 1, 1), 256, 0, stream>>>(
      q_in, Wbq, Qp, bq, nullptr, 128, 1024, 0, 0, 0);
  gemm_bt_kernel<2, true><<<dim3(1024, 1, 1), 256, 0, stream>>>(
      k_in, Wbk, Kp, nullptr, kpart, 128, 1024, 0, 0, 0);
  gemm_bt_kernel<0, true><<<dim3(1024, 1, 1), 256, 0, stream>>>(
      v_in, Wbv, Vp, nullptr, nullptr, 128, 1024, 0, 0, 0);

  ksm2_kernel<<<16, 256, 0, stream>>>(kpart, colinv);

  ctx_partial_kernel<<<dim3(8, 64), 256, 0, stream>>>(Kp, Vp, ctxpart);
  ctx_reduce_kernel<<<1024, 256, 0, stream>>>(ctxpart, bv, colinv, ctxb);
  mb_kernel<<<dim3(16, 16, 4), 256, 0, stream>>>(Wbo, ctxb, Mb);

  // final: per-batch out = Qp_b @ Mb_b^T + bo (fp32 out), MT=32, z=4
  gemm_bt_kernel<3, false><<<dim3(256, 1, 4), 256, 0, stream>>>(
      Qp, Mb, (float*)d_out, bo, nullptr, 32, 1024,
      (long)4096 * 1024, (long)1024 * 1024, (long)4096 * 1024);
}